// Round 14
// baseline (13835.625 us; speedup 1.0000x reference)
//
#include <hip/hip_runtime.h>

// All ops except the two deliberate FMAs below are per-op rounded.
#pragma clang fp contract(off)

#define BATCH 32
#define NPTS 100000
#define NGROUP 2048
#define NBLK_PER_BATCH 8
#define NPB (NPTS / NBLK_PER_BATCH)   /* 12500 points per block */
#define TPB 512
#define NPT 25                        /* ceil(12500/512) points per thread */
#define TAIL (NPB - (NPT - 1) * TPB)  /* 212 */
#define NWAVE 64                      /* waves per batch = 8 blocks x 8 waves */

typedef unsigned long long u64;
typedef unsigned int u32;

static_assert(NPB * NBLK_PER_BATCH == NPTS, "block split must be exact");
static_assert(NPT * TPB >= NPB, "per-thread capacity");

// Guaranteed single-instruction IEEE ops (immune to compiler contraction
// decisions in either direction).
__device__ __forceinline__ float fsub_x(float a, float b) {
  float r; asm("v_sub_f32 %0, %1, %2" : "=v"(r) : "v"(a), "v"(b)); return r;
}
__device__ __forceinline__ float fmul_x(float a, float b) {
  float r; asm("v_mul_f32 %0, %1, %2" : "=v"(r) : "v"(a), "v"(b)); return r;
}
__device__ __forceinline__ float fma_x(float a, float b, float c) {
  float r; asm("v_fma_f32 %0, %1, %2, %3" : "=v"(r) : "v"(a), "v"(b), "v"(c)); return r;
}

// XLA-contracted distance (verified exact vs the jax reference, R12/R13):
//   d = fma(dz,dz, fma(dy,dy, dx*dx))
//
// Barrier-free exchange (this round): no __syncthreads, no LDS. Each of the
// 64 waves of a batch publishes its own candidate {distbits|tag|~idx} to
// slots[b][parity][wave] (relaxed agent-scope store), then every wave polls
// all 64 slots (lane l polls slot l) until all tags match t, and redundantly
// shuffle-reduces the 64 packed values to the identical global winner.
// Argmax-with-lowest-idx is associative, so 64 wave-partitions give the same
// result as the 8 block-partitions that passed R12/R13.
// Lap-around safety: a wave reaches iteration t+2 (overwriting parity t&1)
// only after ALL waves published t+1, which strictly follows their final
// parity-(t&1) read. Slots memset to 0xFF per call (tag 0x7FFF never valid).
// All 256 blocks co-resident (1 block/CU at launch_bounds 512,2): no deadlock.
__global__ __launch_bounds__(TPB, 2)
void fps_kernel(const float* __restrict__ xyz,
                const int* __restrict__ finit,
                float* __restrict__ out,
                u64* __restrict__ slots)
{
  const int blk  = blockIdx.x;
  const int b    = blk & (BATCH - 1);   // batch id
  const int j    = blk >> 5;            // sub-block 0..7 within batch
  const int tid  = threadIdx.x;
  const int lane = tid & 63;
  const int wid  = tid >> 6;
  const int gw   = j * 8 + wid;         // global wave id within batch, 0..63

  const float* xb = xyz + (size_t)b * NPTS * 3;
  const int base = j * NPB;

  // register-resident point coords + f32 running min distance
  float px[NPT], py[NPT], pz[NPT], pd[NPT];
#pragma unroll
  for (int i = 0; i < NPT; ++i) {
    const bool valid = (i < NPT - 1) || (tid < TAIL);
    const int p  = valid ? (tid + i * TPB) : 0;
    const int gp = base + p;
    px[i] = xb[gp * 3 + 0];
    py[i] = xb[gp * 3 + 1];
    pz[i] = xb[gp * 3 + 2];
    pd[i] = valid ? 1.0e10f : -1.0f;   // invalid pads can never win argmax
  }

  int cur = finit[b];   // int32 delivery (established R8==R5, R1==R2)

  float cx = xb[cur * 3 + 0], cy = xb[cur * 3 + 1], cz = xb[cur * 3 + 2];

  u64* bs = slots + (size_t)b * 2 * NWAVE;   // [parity][wave]

  for (int t = 0; t < NGROUP; ++t) {
    if (t == NGROUP - 1) {
      // final output row: no further update needed
      if (j == 0 && tid == 0) {
        float* o = out + ((size_t)b * NGROUP + t) * 3;
        o[0] = cx; o[1] = cy; o[2] = cz;
      }
      break;
    }

    // --- distance min-update + thread-local argmax (first-max wins) ---
    float bestv = -1.0f;
    int   besti = 0x7fffffff;
#pragma unroll
    for (int i = 0; i < NPT; ++i) {
      const bool valid = (i < NPT - 1) || (tid < TAIL);
      const float dx = fsub_x(px[i], cx);
      const float dy = fsub_x(py[i], cy);
      const float dz = fsub_x(pz[i], cz);
      const float d  = fma_x(dz, dz, fma_x(dy, dy, fmul_x(dx, dx)));
      if (valid) {
        const float nd = fminf(pd[i], d);   // jnp.minimum
        pd[i] = nd;
        if (nd > bestv) { bestv = nd; besti = base + tid + i * TPB; }  // strict >: lowest idx
      }
    }

    // --- pack {distbits | tag | ~idx} and wave-reduce by u64 max ---
    // dist bits high (non-negative floats compare as uint); ~idx low so the
    // lower index wins ties; tag in bits [31:17] validates liveness.
    const u32 tag = (u32)(t & 0x7FFF);
    u64 pk = ((u64)__float_as_uint(bestv) << 32)
           | ((u64)tag << 17)
           | (u64)((~(u32)besti) & 0x1FFFFu);
#pragma unroll
    for (int off = 32; off > 0; off >>= 1) {
      const u64 o = __shfl_xor(pk, off, 64);
      if (o > pk) pk = o;
    }

    // --- publish wave candidate ---
    const int par = t & 1;
    u64* wave_slot = bs + (size_t)par * NWAVE + gw;
    if (lane == 0) {
      __hip_atomic_store(wave_slot, pk, __ATOMIC_RELAXED,
                         __HIP_MEMORY_SCOPE_AGENT);
    }

    // output row for iteration t (pre-update centroid) — off the critical
    // path: issued after publish, overlaps the poll
    if (j == 0 && tid == 0) {
      float* o = out + ((size_t)b * NGROUP + t) * 3;
      o[0] = cx; o[1] = cy; o[2] = cz;
    }

    // --- poll: lane l watches slot l until all 64 tags match t ---
    u64* rp = bs + (size_t)par * NWAVE + lane;
    u64 got;
    do {
      got = __hip_atomic_load(rp, __ATOMIC_RELAXED, __HIP_MEMORY_SCOPE_AGENT);
    } while (!__all(((u32)(got >> 17) & 0x7FFFu) == tag));

    // --- reduce the 64 candidates (identical result in every wave) ---
#pragma unroll
    for (int off = 32; off > 0; off >>= 1) {
      const u64 o = __shfl_xor(got, off, 64);
      if (o > got) got = o;
    }
    cur = (int)((~(u32)got) & 0x1FFFFu);

    // reload centroid coords from read-only xyz (always coherent)
    cx = xb[cur * 3 + 0];
    cy = xb[cur * 3 + 1];
    cz = xb[cur * 3 + 2];
  }
}

extern "C" void kernel_launch(void* const* d_in, const int* in_sizes, int n_in,
                              void* d_out, int out_size, void* d_ws, size_t ws_size,
                              hipStream_t stream) {
  const float* xyz   = (const float*)d_in[0];
  const int*   finit = (const int*)d_in[1];
  float*       out   = (float*)d_out;
  u64*         slots = (u64*)d_ws;   // 32 batches x 2 parity x 64 waves x 8 B = 32 KB

  // Invalidate all exchange slots every call (tag bits -> 0x7FFF, never a
  // valid iteration tag). Capture-safe.
  hipMemsetAsync(d_ws, 0xFF, (size_t)BATCH * 2 * NWAVE * sizeof(u64), stream);

  fps_kernel<<<dim3(BATCH * NBLK_PER_BATCH), dim3(TPB), 0, stream>>>(xyz, finit, out, slots);
}

// Round 15
// 5030.936 us; speedup vs baseline: 2.7501x; 2.7501x over previous
//
#include <hip/hip_runtime.h>

// All ops except the two deliberate FMAs below are per-op rounded.
#pragma clang fp contract(off)

#define BATCH 32
#define NPTS 100000
#define NGROUP 2048
#define NBLK_PER_BATCH 8
#define NPB (NPTS / NBLK_PER_BATCH)   /* 12500 points per block */
#define TPB 512
#define NPT 25                        /* ceil(12500/512) points per thread */
#define TAIL (NPB - (NPT - 1) * TPB)  /* 212 */

typedef unsigned long long u64;
typedef unsigned int u32;

static_assert(NPB * NBLK_PER_BATCH == NPTS, "block split must be exact");
static_assert(NPT * TPB >= NPB, "per-thread capacity");

// Guaranteed single-instruction IEEE ops (immune to compiler contraction
// decisions in either direction).
__device__ __forceinline__ float fsub_x(float a, float b) {
  float r; asm("v_sub_f32 %0, %1, %2" : "=v"(r) : "v"(a), "v"(b)); return r;
}
__device__ __forceinline__ float fmul_x(float a, float b) {
  float r; asm("v_mul_f32 %0, %1, %2" : "=v"(r) : "v"(a), "v"(b)); return r;
}
__device__ __forceinline__ float fma_x(float a, float b, float c) {
  float r; asm("v_fma_f32 %0, %1, %2, %3" : "=v"(r) : "v"(a), "v"(b), "v"(c)); return r;
}

#define LD_WG(p)    __hip_atomic_load((p),  __ATOMIC_RELAXED, __HIP_MEMORY_SCOPE_WORKGROUP)
#define ST_WG(p,v)  __hip_atomic_store((p), (v), __ATOMIC_RELAXED, __HIP_MEMORY_SCOPE_WORKGROUP)
#define LD_AG(p)    __hip_atomic_load((p),  __ATOMIC_RELAXED, __HIP_MEMORY_SCOPE_AGENT)
#define ST_AG(p,v)  __hip_atomic_store((p), (v), __ATOMIC_RELAXED, __HIP_MEMORY_SCOPE_AGENT)

// Packed candidate: distbits[63:32] | tag[31:17] | ~idx[16:0].
// Tag bits are ZERO during reductions (comparisons unaffected — equal in all
// operands) and OR'd in when a word becomes a cross-wave/cross-block message.
// ~idx in the low bits makes u64-max pick the LOWEST index on distance ties.
// LDS release word: coordbits[63:32] | tag[31:17] | 0.
// All handshakes are tagged + parity-double-buffered; stale/garbage content
// just spins (tag 0x7FFF from init never matches t <= 2046).
__global__ __launch_bounds__(TPB, 2)
void fps_kernel(const float* __restrict__ xyz,
                const int* __restrict__ finit,
                float* __restrict__ out,
                u64* __restrict__ slots)
{
  const int blk  = blockIdx.x;
  const int b    = blk & (BATCH - 1);   // batch id
  const int j    = blk >> 5;            // sub-block 0..7 within batch
  const int tid  = threadIdx.x;
  const int lane = tid & 63;
  const int wid  = tid >> 6;

  __shared__ u64 sval[2][8];   // [parity][wave] tagged candidates
  __shared__ u64 srel[2][3];   // [parity][cx,cy,cz] tagged release words

  // invalidate LDS tags (0x7FFF), once; the only barrier in the kernel
  if (tid < 16) sval[tid >> 3][tid & 7] = ~0ull;
  if (tid >= 16 && tid < 22) srel[(tid - 16) / 3][(tid - 16) % 3] = ~0ull;
  __syncthreads();

  const float* xb = xyz + (size_t)b * NPTS * 3;
  const int base = j * NPB;

  // register-resident point coords + f32 running min distance
  float px[NPT], py[NPT], pz[NPT], pd[NPT];
#pragma unroll
  for (int i = 0; i < NPT; ++i) {
    const bool valid = (i < NPT - 1) || (tid < TAIL);
    const int p  = valid ? (tid + i * TPB) : 0;
    const int gp = base + p;
    px[i] = xb[gp * 3 + 0];
    py[i] = xb[gp * 3 + 1];
    pz[i] = xb[gp * 3 + 2];
    pd[i] = valid ? 1.0e10f : -1.0f;   // invalid pads can never win argmax
  }

  const int cur0 = finit[b];   // int32 delivery (established R8==R5, R1==R2)
  float cx = xb[cur0 * 3 + 0], cy = xb[cur0 * 3 + 1], cz = xb[cur0 * 3 + 2];

  u64* gs = slots + (size_t)b * 2 * NBLK_PER_BATCH;   // [parity][block], 64B/parity

  for (int t = 0; t < NGROUP; ++t) {
    // record current farthest (pre-update); wid1 keeps this off wave 0's path
    if (j == 0 && wid == 1 && lane == 0) {
      float* o = out + ((size_t)b * NGROUP + t) * 3;
      o[0] = cx; o[1] = cy; o[2] = cz;
    }
    if (t == NGROUP - 1) break;   // uniform exit

    const int p   = t & 1;
    const u32 tag = (u32)(t & 0x7FFF);

    // --- distance min-update + thread-local argmax (first-max wins) ---
    float bestv = -1.0f;
    int   besti = 0x7fffffff;
#pragma unroll
    for (int i = 0; i < NPT; ++i) {
      const bool valid = (i < NPT - 1) || (tid < TAIL);
      const float dx = fsub_x(px[i], cx);
      const float dy = fsub_x(py[i], cy);
      const float dz = fsub_x(pz[i], cz);
      const float d  = fma_x(dz, dz, fma_x(dy, dy, fmul_x(dx, dx)));   // XLA-contracted (R12-verified)
      if (valid) {
        const float nd = fminf(pd[i], d);   // jnp.minimum
        pd[i] = nd;
        if (nd > bestv) { bestv = nd; besti = base + tid + i * TPB; }  // strict >: lowest idx
      }
    }

    // --- wave-level u64-max reduce ---
    u64 pk = ((u64)__float_as_uint(bestv) << 32) | (u64)((~(u32)besti) & 0x1FFFFu);
#pragma unroll
    for (int off = 32; off > 0; off >>= 1) {
      const u64 o = __shfl_xor(pk, off, 64);
      if (o > pk) pk = o;
    }
    if (lane == 0) ST_WG(&sval[p][wid], pk | ((u64)tag << 17));

    float ncx, ncy, ncz;
    if (wid == 0) {
      // --- gather the 8 wave candidates via tagged-LDS spin (no barrier) ---
      u64 sv;
      do {
        sv = (lane < 8) ? LD_WG(&sval[p][lane]) : 0ull;
      } while (!__all(lane >= 8 || (((u32)(sv >> 17) & 0x7FFFu) == tag)));
#pragma unroll
      for (int off = 4; off > 0; off >>= 1) {
        const u64 o = __shfl_xor(sv, off, 64);
        if (o > sv) sv = o;
      }
      // --- publish block candidate, poll the batch's 64B slot line ---
      if (lane == 0) ST_AG(gs + p * NBLK_PER_BATCH + j, sv);
      u64 gv;
      do {
        gv = (lane < NBLK_PER_BATCH) ? LD_AG(gs + p * NBLK_PER_BATCH + lane) : 0ull;
      } while (!__all(lane >= NBLK_PER_BATCH || (((u32)(gv >> 17) & 0x7FFFu) == tag)));

      // --- speculative coord prefetch for all 8 candidates (hides the
      //     dependent centroid load under the final reduce) ---
      float fx = 0.f, fy = 0.f, fz = 0.f;
      if (lane < NBLK_PER_BATCH) {
        const int cand = (int)((~(u32)gv) & 0x1FFFFu);
        const float* cp = xb + (size_t)cand * 3;
        fx = cp[0]; fy = cp[1]; fz = cp[2];
      }
      u64 win = gv;   // lanes >= 8 hold 0 (can never win: ~idx low bits > 0)
#pragma unroll
      for (int off = 4; off > 0; off >>= 1) {
        const u64 o = __shfl_xor(win, off, 64);
        if (o > win) win = o;
      }
      const u64 wmax = __shfl(win, 0, 64);
      const u64 mask = __ballot(lane < NBLK_PER_BATCH && gv == wmax);
      const int w    = (int)__ffsll((long long)mask) - 1;
      ncx = __shfl(fx, w, 64); ncy = __shfl(fy, w, 64); ncz = __shfl(fz, w, 64);

      // --- release the block: 3 self-validating tagged words ---
      if (lane == 0) {
        const u64 lo = (u64)tag << 17;
        ST_WG(&srel[p][0], ((u64)__float_as_uint(ncx) << 32) | lo);
        ST_WG(&srel[p][1], ((u64)__float_as_uint(ncy) << 32) | lo);
        ST_WG(&srel[p][2], ((u64)__float_as_uint(ncz) << 32) | lo);
      }
    } else {
      // --- wait for release, pick up new centroid coords from LDS ---
      u64 rv;
      do {
        rv = (lane < 3) ? LD_WG(&srel[p][lane]) : 0ull;
      } while (!__all(lane >= 3 || (((u32)(rv >> 17) & 0x7FFFu) == tag)));
      const float f = __uint_as_float((u32)(rv >> 32));
      ncx = __shfl(f, 0, 64); ncy = __shfl(f, 1, 64); ncz = __shfl(f, 2, 64);
    }

    cx = ncx; cy = ncy; cz = ncz;
  }
}

extern "C" void kernel_launch(void* const* d_in, const int* in_sizes, int n_in,
                              void* d_out, int out_size, void* d_ws, size_t ws_size,
                              hipStream_t stream) {
  const float* xyz   = (const float*)d_in[0];
  const int*   finit = (const int*)d_in[1];
  float*       out   = (float*)d_out;
  u64*         slots = (u64*)d_ws;   // 32 x 2 x 8 u64 = 4 KB exchange slots

  // Invalidate all global slots every call (tag -> 0x7FFF, never valid).
  hipMemsetAsync(d_ws, 0xFF,
                 (size_t)BATCH * 2 * NBLK_PER_BATCH * sizeof(u64), stream);

  fps_kernel<<<dim3(BATCH * NBLK_PER_BATCH), dim3(TPB), 0, stream>>>(xyz, finit, out, slots);
}

// Round 16
// 4947.960 us; speedup vs baseline: 2.7962x; 1.0168x over previous
//
#include <hip/hip_runtime.h>

// All ops except the two deliberate FMAs below are per-op rounded.
#pragma clang fp contract(off)

#define BATCH 32
#define NPTS 100000
#define NGROUP 2048
#define NBLK_PER_BATCH 8
#define NPB (NPTS / NBLK_PER_BATCH)   /* 12500 points per block */
#define TPB 512
#define NPT 25                        /* ceil(12500/512) points per thread */
#define TAIL (NPB - (NPT - 1) * TPB)  /* 212 */

typedef unsigned long long u64;
typedef unsigned int u32;

static_assert(NPB * NBLK_PER_BATCH == NPTS, "block split must be exact");
static_assert(NPT * TPB >= NPB, "per-thread capacity");

// Guaranteed single-instruction IEEE ops (immune to compiler contraction
// decisions in either direction).
__device__ __forceinline__ float fsub_x(float a, float b) {
  float r; asm("v_sub_f32 %0, %1, %2" : "=v"(r) : "v"(a), "v"(b)); return r;
}
__device__ __forceinline__ float fmul_x(float a, float b) {
  float r; asm("v_mul_f32 %0, %1, %2" : "=v"(r) : "v"(a), "v"(b)); return r;
}
__device__ __forceinline__ float fma_x(float a, float b, float c) {
  float r; asm("v_fma_f32 %0, %1, %2, %3" : "=v"(r) : "v"(a), "v"(b), "v"(c)); return r;
}

#define LD_WG(p)    __hip_atomic_load((p),  __ATOMIC_RELAXED, __HIP_MEMORY_SCOPE_WORKGROUP)
#define ST_WG(p,v)  __hip_atomic_store((p), (v), __ATOMIC_RELAXED, __HIP_MEMORY_SCOPE_WORKGROUP)
#define LD_AG(p)    __hip_atomic_load((p),  __ATOMIC_RELAXED, __HIP_MEMORY_SCOPE_AGENT)
#define ST_AG(p,v)  __hip_atomic_store((p), (v), __ATOMIC_RELAXED, __HIP_MEMORY_SCOPE_AGENT)

// Packed candidate: distbits[63:32] | tag[31:17] | ~idx[16:0].
// Tag bits are ZERO during reductions (equal in all operands) and OR'd in
// when a word becomes a cross-wave/cross-block message. ~idx in the low bits
// makes u64-max pick the LOWEST index on distance ties.
// LDS release word: coordbits[63:32] | tag[31:17] | 0.
// All handshakes are tagged + parity-double-buffered; stale/garbage content
// just spins (tag 0x7FFF from init never matches t <= 2046).
//
// __launch_bounds__(512, 1): 256 blocks on 256 CUs = 1 block/CU. The "min 2
// blocks/CU" in R12-R15 capped the allocator at 128 VGPR and silently demoted
// px/py/pz/pd[25] (100 f32/thread) to scratch (VGPR_Count=84, WRITE_SIZE 17MB
// vs 0.78MB output) — the inner loop was L2-BW-bound on array re-reads.
// At min=1 the budget is 256 VGPR and the arrays live in registers.
__global__ __launch_bounds__(TPB, 1)
void fps_kernel(const float* __restrict__ xyz,
                const int* __restrict__ finit,
                float* __restrict__ out,
                u64* __restrict__ slots)
{
  const int blk  = blockIdx.x;
  const int b    = blk & (BATCH - 1);   // batch id
  const int j    = blk >> 5;            // sub-block 0..7 within batch
  const int tid  = threadIdx.x;
  const int lane = tid & 63;
  const int wid  = tid >> 6;

  __shared__ u64 sval[2][8];   // [parity][wave] tagged candidates
  __shared__ u64 srel[2][3];   // [parity][cx,cy,cz] tagged release words

  // invalidate LDS tags (0x7FFF), once; the only barrier in the kernel
  if (tid < 16) sval[tid >> 3][tid & 7] = ~0ull;
  if (tid >= 16 && tid < 22) srel[(tid - 16) / 3][(tid - 16) % 3] = ~0ull;
  __syncthreads();

  const float* xb = xyz + (size_t)b * NPTS * 3;
  const int base = j * NPB;

  // register-resident point coords + f32 running min distance
  float px[NPT], py[NPT], pz[NPT], pd[NPT];
#pragma unroll
  for (int i = 0; i < NPT; ++i) {
    const bool valid = (i < NPT - 1) || (tid < TAIL);
    const int p  = valid ? (tid + i * TPB) : 0;
    const int gp = base + p;
    px[i] = xb[gp * 3 + 0];
    py[i] = xb[gp * 3 + 1];
    pz[i] = xb[gp * 3 + 2];
    pd[i] = valid ? 1.0e10f : -1.0f;   // invalid pads can never win argmax
  }

  const int cur0 = finit[b];   // int32 delivery (established R8==R5, R1==R2)
  float cx = xb[cur0 * 3 + 0], cy = xb[cur0 * 3 + 1], cz = xb[cur0 * 3 + 2];

  u64* gs = slots + (size_t)b * 2 * NBLK_PER_BATCH;   // [parity][block], 64B/parity

  for (int t = 0; t < NGROUP; ++t) {
    // record current farthest (pre-update); wid1 keeps this off wave 0's path
    if (j == 0 && wid == 1 && lane == 0) {
      float* o = out + ((size_t)b * NGROUP + t) * 3;
      o[0] = cx; o[1] = cy; o[2] = cz;
    }
    if (t == NGROUP - 1) break;   // uniform exit

    const int p   = t & 1;
    const u32 tag = (u32)(t & 0x7FFF);

    // --- distance min-update + thread-local argmax (first-max wins) ---
    float bestv = -1.0f;
    int   besti = 0x7fffffff;
#pragma unroll
    for (int i = 0; i < NPT; ++i) {
      const bool valid = (i < NPT - 1) || (tid < TAIL);
      const float dx = fsub_x(px[i], cx);
      const float dy = fsub_x(py[i], cy);
      const float dz = fsub_x(pz[i], cz);
      const float d  = fma_x(dz, dz, fma_x(dy, dy, fmul_x(dx, dx)));   // XLA-contracted (R12-verified)
      if (valid) {
        const float nd = fminf(pd[i], d);   // jnp.minimum
        pd[i] = nd;
        if (nd > bestv) { bestv = nd; besti = base + tid + i * TPB; }  // strict >: lowest idx
      }
    }

    // --- wave-level u64-max reduce ---
    u64 pk = ((u64)__float_as_uint(bestv) << 32) | (u64)((~(u32)besti) & 0x1FFFFu);
#pragma unroll
    for (int off = 32; off > 0; off >>= 1) {
      const u64 o = __shfl_xor(pk, off, 64);
      if (o > pk) pk = o;
    }
    if (lane == 0) ST_WG(&sval[p][wid], pk | ((u64)tag << 17));

    float ncx, ncy, ncz;
    if (wid == 0) {
      // --- gather the 8 wave candidates via tagged-LDS spin (no barrier) ---
      u64 sv;
      do {
        sv = (lane < 8) ? LD_WG(&sval[p][lane]) : 0ull;
      } while (!__all(lane >= 8 || (((u32)(sv >> 17) & 0x7FFFu) == tag)));
#pragma unroll
      for (int off = 4; off > 0; off >>= 1) {
        const u64 o = __shfl_xor(sv, off, 64);
        if (o > sv) sv = o;
      }
      // --- publish block candidate, poll the batch's 64B slot line ---
      if (lane == 0) ST_AG(gs + p * NBLK_PER_BATCH + j, sv);
      u64 gv;
      do {
        gv = (lane < NBLK_PER_BATCH) ? LD_AG(gs + p * NBLK_PER_BATCH + lane) : 0ull;
      } while (!__all(lane >= NBLK_PER_BATCH || (((u32)(gv >> 17) & 0x7FFFu) == tag)));

      // --- speculative coord prefetch for all 8 candidates (hides the
      //     dependent centroid load under the final reduce) ---
      float fx = 0.f, fy = 0.f, fz = 0.f;
      if (lane < NBLK_PER_BATCH) {
        const int cand = (int)((~(u32)gv) & 0x1FFFFu);
        const float* cp = xb + (size_t)cand * 3;
        fx = cp[0]; fy = cp[1]; fz = cp[2];
      }
      u64 win = gv;   // lanes >= 8 hold 0 (can never win: ~idx low bits > 0)
#pragma unroll
      for (int off = 4; off > 0; off >>= 1) {
        const u64 o = __shfl_xor(win, off, 64);
        if (o > win) win = o;
      }
      const u64 wmax = __shfl(win, 0, 64);
      const u64 mask = __ballot(lane < NBLK_PER_BATCH && gv == wmax);
      const int w    = (int)__ffsll((long long)mask) - 1;
      ncx = __shfl(fx, w, 64); ncy = __shfl(fy, w, 64); ncz = __shfl(fz, w, 64);

      // --- release the block: 3 self-validating tagged words ---
      if (lane == 0) {
        const u64 lo = (u64)tag << 17;
        ST_WG(&srel[p][0], ((u64)__float_as_uint(ncx) << 32) | lo);
        ST_WG(&srel[p][1], ((u64)__float_as_uint(ncy) << 32) | lo);
        ST_WG(&srel[p][2], ((u64)__float_as_uint(ncz) << 32) | lo);
      }
    } else {
      // --- wait for release, pick up new centroid coords from LDS ---
      u64 rv;
      do {
        rv = (lane < 3) ? LD_WG(&srel[p][lane]) : 0ull;
      } while (!__all(lane >= 3 || (((u32)(rv >> 17) & 0x7FFFu) == tag)));
      const float f = __uint_as_float((u32)(rv >> 32));
      ncx = __shfl(f, 0, 64); ncy = __shfl(f, 1, 64); ncz = __shfl(f, 2, 64);
    }

    cx = ncx; cy = ncy; cz = ncz;
  }
}

extern "C" void kernel_launch(void* const* d_in, const int* in_sizes, int n_in,
                              void* d_out, int out_size, void* d_ws, size_t ws_size,
                              hipStream_t stream) {
  const float* xyz   = (const float*)d_in[0];
  const int*   finit = (const int*)d_in[1];
  float*       out   = (float*)d_out;
  u64*         slots = (u64*)d_ws;   // 32 x 2 x 8 u64 = 4 KB exchange slots

  // Invalidate all global slots every call (tag -> 0x7FFF, never valid).
  hipMemsetAsync(d_ws, 0xFF,
                 (size_t)BATCH * 2 * NBLK_PER_BATCH * sizeof(u64), stream);

  fps_kernel<<<dim3(BATCH * NBLK_PER_BATCH), dim3(TPB), 0, stream>>>(xyz, finit, out, slots);
}